// Round 6
// baseline (26.058 us; speedup 1.0000x reference)
//
#include <hip/hip_runtime.h>

// IPN layer: per batch b, X = x[b] (64 rows x 32 cols, fp32).
// out[b, p] = dot(X[i], X[j]) for row-major strict-upper pairs (i<j), packed.
// B=8192, F=64, E=32, PAIRS = 2016.
//
// MFMA formulation: gram tile (p,q) = mfma_f32_16x16x32_bf16(frag[p], frag[q]);
// the same lane-fragment serves as both A and B for X·X^T. One wave per
// batch, no barriers (LDS regions are wave-private).
//
// Epilogue: scatter packed strict-upper values into wave-private LDS, then
// stream out as dense aligned f32x4 stores (8064 B/batch = 63 full 128B
// lines, line-aligned). R6: regular (cache-routed) stores instead of
// nontemporal — A/B test of the NT store path.

#define FDIM 64
#define EDIM 32
#define PAIRS 2016

typedef __attribute__((ext_vector_type(8))) short bf16x8;
typedef __attribute__((ext_vector_type(4))) float f32x4;

static __device__ __forceinline__ short f2bf(float f) {
    union { float f; unsigned u; } v; v.f = f;
    unsigned r = v.u + 0x7FFFu + ((v.u >> 16) & 1u);   // RNE truncate to bf16
    return (short)(r >> 16);
}

__global__ __launch_bounds__(256, 4) void ipn_mfma_kernel(const float* __restrict__ x,
                                                          float* __restrict__ out) {
    __shared__ float pbuf[4][2048];    // 4 waves * 8 KiB packed-output staging

    const int tid = threadIdx.x;
    const int w   = tid >> 6;          // wave in block
    const int l   = tid & 63;          // lane
    const int b   = blockIdx.x * 4 + w;

    const int r16 = l & 15;            // row-within-16-block (also col for B role)
    const int kb  = (l >> 4) * 8;      // k-base for this lane

    const float* xb = x + (size_t)b * (FDIM * EDIM);

    // ---- load + convert the 4 row-block fragments ----
    bf16x8 frag[4];
    #pragma unroll
    for (int p = 0; p < 4; ++p) {
        const float* rp = xb + (p * 16 + r16) * EDIM + kb;
        f32x4 lo = *(const f32x4*)(rp);
        f32x4 hi = *(const f32x4*)(rp + 4);
        bf16x8 f;
        f[0] = f2bf(lo.x); f[1] = f2bf(lo.y); f[2] = f2bf(lo.z); f[3] = f2bf(lo.w);
        f[4] = f2bf(hi.x); f[5] = f2bf(hi.y); f[6] = f2bf(hi.z); f[7] = f2bf(hi.w);
        frag[p] = f;
    }

    // ---- 10 upper-triangle 16x16 tiles ----
    f32x4 acc[10];
    #pragma unroll
    for (int t = 0; t < 10; ++t) acc[t] = (f32x4)(0.0f);
    {
        int idx = 0;
        #pragma unroll
        for (int p = 0; p < 4; ++p)
            #pragma unroll
            for (int q = p; q < 4; ++q) {
                acc[idx] = __builtin_amdgcn_mfma_f32_16x16x32_bf16(
                    frag[p], frag[q], acc[idx], 0, 0, 0);
                ++idx;
            }
    }

    // ---- scatter packed values into wave-private LDS ----
    // C/D layout: col = lane&15, row = (lane>>4)*4 + reg   [m89]
    // packed pos(i,j) = i*(127-i)/2 + (j - i - 1)
    float* pb = pbuf[w];
    const int jc = r16;
    const int ir = (l >> 4) * 4;
    {
        int idx = 0;
        #pragma unroll
        for (int p = 0; p < 4; ++p)
            #pragma unroll
            for (int q = p; q < 4; ++q) {
                const int jg = q * 16 + jc;
                #pragma unroll
                for (int t = 0; t < 4; ++t) {
                    const int ig = p * 16 + ir + t;
                    if (p < q || jg > ig) {
                        const int base = ig * (2 * FDIM - 1 - ig) / 2 - ig - 1;
                        pb[base + jg] = acc[idx][t];
                    }
                }
                ++idx;
            }
    }
    // wave-private producer/consumer: compiler's lgkmcnt ordering, no barrier

    // ---- dense f32x4 stream-out (504 float4 per batch), cache-routed ----
    const f32x4* pb4 = (const f32x4*)pb;
    f32x4* ob4 = (f32x4*)(out + (size_t)b * PAIRS);
    #pragma unroll
    for (int it = 0; it < 8; ++it) {
        const int idx4 = it * 64 + l;
        if (idx4 < 504) {
            ob4[idx4] = pb4[idx4];
        }
    }
}

extern "C" void kernel_launch(void* const* d_in, const int* in_sizes, int n_in,
                              void* d_out, int out_size, void* d_ws, size_t ws_size,
                              hipStream_t stream) {
    const float* x = (const float*)d_in[0];
    float* out = (float*)d_out;
    const int nb = in_sizes[0] / (FDIM * EDIM);   // 8192 batches
    const int grid = nb / 4;                      // 4 batches (waves) per block
    ipn_mfma_kernel<<<grid, 256, 0, stream>>>(x, out);
}

// Round 7
// 25.819 us; speedup vs baseline: 1.0093x; 1.0093x over previous
//
#include <hip/hip_runtime.h>

// IPN layer: per batch b, X = x[b] (64 rows x 32 cols, fp32).
// out[b, p] = dot(X[i], X[j]) for row-major strict-upper pairs (i<j), packed.
// B=8192, F=64, E=32, PAIRS = 2016.
//
// MFMA formulation: gram tile (p,q) = mfma_f32_16x16x32_bf16(frag[p], frag[q]);
// the same lane-fragment serves as both A and B for X·X^T. One wave per
// batch, no barriers (LDS regions are wave-private).
//
// Epilogue: scatter packed strict-upper values into wave-private LDS, then
// stream out as dense aligned f32x4 NONTEMPORAL stores (8064 B/batch = 63
// full 128B lines). NT stores keep the 64MB input L3-resident across
// replays (A/B verified: NT 25.30us vs cache-routed 26.06us).
// Best-measured variant (R4): 25.30 us ~= 5.1 TB/s mixed-stream, ~82% of
// the 6.29 TB/s copy ceiling.

#define FDIM 64
#define EDIM 32
#define PAIRS 2016

typedef __attribute__((ext_vector_type(8))) short bf16x8;
typedef __attribute__((ext_vector_type(4))) float f32x4;

static __device__ __forceinline__ short f2bf(float f) {
    union { float f; unsigned u; } v; v.f = f;
    unsigned r = v.u + 0x7FFFu + ((v.u >> 16) & 1u);   // RNE truncate to bf16
    return (short)(r >> 16);
}

__global__ __launch_bounds__(256, 4) void ipn_mfma_kernel(const float* __restrict__ x,
                                                          float* __restrict__ out) {
    __shared__ float pbuf[4][2048];    // 4 waves * 8 KiB packed-output staging

    const int tid = threadIdx.x;
    const int w   = tid >> 6;          // wave in block
    const int l   = tid & 63;          // lane
    const int b   = blockIdx.x * 4 + w;

    const int r16 = l & 15;            // row-within-16-block (also col for B role)
    const int kb  = (l >> 4) * 8;      // k-base for this lane

    const float* xb = x + (size_t)b * (FDIM * EDIM);

    // ---- load + convert the 4 row-block fragments ----
    bf16x8 frag[4];
    #pragma unroll
    for (int p = 0; p < 4; ++p) {
        const float* rp = xb + (p * 16 + r16) * EDIM + kb;
        f32x4 lo = *(const f32x4*)(rp);
        f32x4 hi = *(const f32x4*)(rp + 4);
        bf16x8 f;
        f[0] = f2bf(lo.x); f[1] = f2bf(lo.y); f[2] = f2bf(lo.z); f[3] = f2bf(lo.w);
        f[4] = f2bf(hi.x); f[5] = f2bf(hi.y); f[6] = f2bf(hi.z); f[7] = f2bf(hi.w);
        frag[p] = f;
    }

    // ---- 10 upper-triangle 16x16 tiles ----
    f32x4 acc[10];
    #pragma unroll
    for (int t = 0; t < 10; ++t) acc[t] = (f32x4)(0.0f);
    {
        int idx = 0;
        #pragma unroll
        for (int p = 0; p < 4; ++p)
            #pragma unroll
            for (int q = p; q < 4; ++q) {
                acc[idx] = __builtin_amdgcn_mfma_f32_16x16x32_bf16(
                    frag[p], frag[q], acc[idx], 0, 0, 0);
                ++idx;
            }
    }

    // ---- scatter packed values into wave-private LDS ----
    // C/D layout: col = lane&15, row = (lane>>4)*4 + reg   [m89]
    // packed pos(i,j) = i*(127-i)/2 + (j - i - 1)
    float* pb = pbuf[w];
    const int jc = r16;
    const int ir = (l >> 4) * 4;
    {
        int idx = 0;
        #pragma unroll
        for (int p = 0; p < 4; ++p)
            #pragma unroll
            for (int q = p; q < 4; ++q) {
                const int jg = q * 16 + jc;
                #pragma unroll
                for (int t = 0; t < 4; ++t) {
                    const int ig = p * 16 + ir + t;
                    if (p < q || jg > ig) {
                        const int base = ig * (2 * FDIM - 1 - ig) / 2 - ig - 1;
                        pb[base + jg] = acc[idx][t];
                    }
                }
                ++idx;
            }
    }
    // wave-private producer/consumer: compiler's lgkmcnt ordering, no barrier

    // ---- dense nontemporal f32x4 stream-out (504 float4 per batch) ----
    const f32x4* pb4 = (const f32x4*)pb;
    f32x4* ob4 = (f32x4*)(out + (size_t)b * PAIRS);
    #pragma unroll
    for (int it = 0; it < 8; ++it) {
        const int idx4 = it * 64 + l;
        if (idx4 < 504) {
            f32x4 v = pb4[idx4];
            __builtin_nontemporal_store(v, ob4 + idx4);
        }
    }
}

extern "C" void kernel_launch(void* const* d_in, const int* in_sizes, int n_in,
                              void* d_out, int out_size, void* d_ws, size_t ws_size,
                              hipStream_t stream) {
    const float* x = (const float*)d_in[0];
    float* out = (float*)d_out;
    const int nb = in_sizes[0] / (FDIM * EDIM);   // 8192 batches
    const int grid = nb / 4;                      // 4 batches (waves) per block
    ipn_mfma_kernel<<<grid, 256, 0, stream>>>(x, out);
}

// Round 8
// 25.618 us; speedup vs baseline: 1.0172x; 1.0078x over previous
//
#include <hip/hip_runtime.h>

// IPN layer: per batch b, X = x[b] (64 rows x 32 cols, fp32).
// out[b, p] = dot(X[i], X[j]) for row-major strict-upper pairs (i<j), packed.
// B=8192, F=64, E=32, PAIRS = 2016.
//
// MFMA formulation: gram tile (p,q) = mfma_f32_16x16x32_bf16(frag[p], frag[q]);
// the same lane-fragment serves as both A and B for X·X^T. One wave per
// batch, no barriers (LDS regions are wave-private).
//
// R8: high-occupancy epilogue. Packed output splits by row-block p into
// chunks [0,888),[888,1520),[1520,1896),[1896,2016) — each <=1024 floats and
// 16B-aligned. Epilogue runs in 4 passes over a 1024-float wave-private LDS
// buffer (scatter tiles (p,q>=p), NT-stream the chunk, reuse buffer).
// LDS 32->16 KiB/block => 8 blocks/CU (launch_bounds(256,8)), 32 waves/CU.

#define FDIM 64
#define EDIM 32
#define PAIRS 2016

typedef __attribute__((ext_vector_type(8))) short bf16x8;
typedef __attribute__((ext_vector_type(4))) float f32x4;

static __device__ __forceinline__ short f2bf(float f) {
    union { float f; unsigned u; } v; v.f = f;
    unsigned r = v.u + 0x7FFFu + ((v.u >> 16) & 1u);   // RNE truncate to bf16
    return (short)(r >> 16);
}

__global__ __launch_bounds__(256, 8) void ipn_mfma_kernel(const float* __restrict__ x,
                                                          float* __restrict__ out) {
    __shared__ float pbuf[4][1024];    // 4 waves * 4 KiB packed-output staging

    const int tid = threadIdx.x;
    const int w   = tid >> 6;          // wave in block
    const int l   = tid & 63;          // lane
    const int b   = blockIdx.x * 4 + w;

    const int r16 = l & 15;            // row-within-16-block (also col for B role)
    const int kb  = (l >> 4) * 8;      // k-base for this lane

    const float* xb = x + (size_t)b * (FDIM * EDIM);

    // ---- load + convert the 4 row-block fragments ----
    bf16x8 frag[4];
    #pragma unroll
    for (int p = 0; p < 4; ++p) {
        const float* rp = xb + (p * 16 + r16) * EDIM + kb;
        f32x4 lo = *(const f32x4*)(rp);
        f32x4 hi = *(const f32x4*)(rp + 4);
        bf16x8 f;
        f[0] = f2bf(lo.x); f[1] = f2bf(lo.y); f[2] = f2bf(lo.z); f[3] = f2bf(lo.w);
        f[4] = f2bf(hi.x); f[5] = f2bf(hi.y); f[6] = f2bf(hi.z); f[7] = f2bf(hi.w);
        frag[p] = f;
    }

    // ---- 10 upper-triangle 16x16 tiles ----
    f32x4 acc[10];
    #pragma unroll
    for (int t = 0; t < 10; ++t) acc[t] = (f32x4)(0.0f);
    {
        int idx = 0;
        #pragma unroll
        for (int p = 0; p < 4; ++p)
            #pragma unroll
            for (int q = p; q < 4; ++q) {
                acc[idx] = __builtin_amdgcn_mfma_f32_16x16x32_bf16(
                    frag[p], frag[q], acc[idx], 0, 0, 0);
                ++idx;
            }
    }

    // ---- 4-pass epilogue: scatter row-block p into LDS, NT-stream chunk ----
    // C/D layout: col = lane&15, row = (lane>>4)*4 + reg   [m89]
    // packed pos(i,j) = i*(127-i)/2 + (j - i - 1); chunk base = off(16p)
    float* pb = pbuf[w];
    float* ob = out + (size_t)b * PAIRS;
    const int jc = r16;
    const int ir = (l >> 4) * 4;

    const int base_p[4] = {0, 888, 1520, 1896};   // off(16p)
    const int n4_p[4]   = {222, 158, 94, 30};     // chunk floats / 4

    {
        int idx = 0;
        #pragma unroll
        for (int p = 0; p < 4; ++p) {
            // scatter tiles (p, q>=p) for rows 16p..16p+15
            #pragma unroll
            for (int q = p; q < 4; ++q) {
                const int jg = q * 16 + jc;
                #pragma unroll
                for (int t = 0; t < 4; ++t) {
                    const int ig = p * 16 + ir + t;
                    if (p < q || jg > ig) {
                        const int pos = ig * (2 * FDIM - 1 - ig) / 2 - ig - 1
                                        + jg - base_p[p];
                        pb[pos] = acc[idx][t];
                    }
                }
                ++idx;
            }
            // stream this chunk (wave-private: compiler lgkmcnt ordering only)
            const f32x4* pb4 = (const f32x4*)pb;
            f32x4* ob4 = (f32x4*)(ob + base_p[p]);
            #pragma unroll
            for (int it = 0; it * 64 < n4_p[p]; ++it) {
                const int idx4 = it * 64 + l;
                if (idx4 < n4_p[p]) {
                    f32x4 v = pb4[idx4];
                    __builtin_nontemporal_store(v, ob4 + idx4);
                }
            }
        }
    }
}

extern "C" void kernel_launch(void* const* d_in, const int* in_sizes, int n_in,
                              void* d_out, int out_size, void* d_ws, size_t ws_size,
                              hipStream_t stream) {
    const float* x = (const float*)d_in[0];
    float* out = (float*)d_out;
    const int nb = in_sizes[0] / (FDIM * EDIM);   // 8192 batches
    const int grid = nb / 4;                      // 4 batches (waves) per block
    ipn_mfma_kernel<<<grid, 256, 0, stream>>>(x, out);
}